// Round 7
// baseline (253.445 us; speedup 1.0000x reference)
//
#include <hip/hip_runtime.h>
#include <hip/hip_bf16.h>

// GCN 'attn' conv, bucketized CSR build with deterministic offsets (R6) +
// lane-per-feature SpMM (R7):
//   out[n] = rsqrt(max(deg_dst[n],1)) * sum_{e: dst==n} y'[src_e] + b
//   y'[j]  = bf16( (x[j] @ W^T) * rsqrt(max(deg_src[j],1)) )
// R6 lesson: spmm's shfl-reduce epilogue (24 ds-ops/node ~ 23 us of LDS-pipe)
// and 48% masked-lane padding were the cost, not the gathers. R7 spmm: wave
// per node, lane = feature, scalar csr loads, no shuffles, no padding.
//
// ws (ints): partial[2NB][NBLK] (bucket-major) | totals[2NB] | bbD[NB+1] |
//   bbS[NB+1] | row_ptr[N+1] | srcfac[N] | entry_pool[E] | key_pool[E]
//   (csr aliases key_pool) | y_bf16[N*64]  (~29 MB). No memset needed.

#define NBLK 512   // hist/scatter blocks: 2 per CU
#define MAXB 512   // max 256-node buckets per stream (N <= 131072)

// K1: per-block LDS histograms; bucket-major partial (coalesced colprefix walk)
__global__ void hist_kernel(const int* __restrict__ idx, int E, int NB,
                            int* __restrict__ partial) {
    __shared__ int h[2 * MAXB];
    int tid = threadIdx.x;
    for (int i = tid; i < 2 * NB; i += blockDim.x) h[i] = 0;
    __syncthreads();
    int stride = gridDim.x * blockDim.x;
    for (int e = blockIdx.x * blockDim.x + tid; e < E; e += stride) {
        atomicAdd(&h[idx[e] >> 8], 1);            // dst bucket (LDS)
        atomicAdd(&h[NB + (idx[E + e] >> 8)], 1); // src bucket (LDS)
    }
    __syncthreads();
    for (int i = tid; i < 2 * NB; i += blockDim.x)
        partial[(size_t)i * NBLK + blockIdx.x] = h[i];
}

// K2a: per-bucket column prefix over blocks (in place) -> totals.
__global__ void colprefix_kernel(int* __restrict__ partial,
                                 int* __restrict__ totals, int NB) {
    int i = blockIdx.x * blockDim.x + threadIdx.x;
    if (i >= 2 * NB) return;
    int* col = partial + (size_t)i * NBLK;
    int acc = 0;
    for (int b = 0; b < NBLK; ++b) {
        int t = col[b];
        col[b] = acc;          // exclusive per-block offset within bucket
        acc += t;
    }
    totals[i] = acc;
}

// K2b: exclusive scans of bucket totals -> bbD (dst stream), bbS (src stream).
__global__ void scan_kernel(const int* __restrict__ totals, int NB, int E, int N,
                            int* __restrict__ bbD, int* __restrict__ bbS,
                            int* __restrict__ row_ptr) {
    __shared__ int sc[MAXB];
    int tid = threadIdx.x;  // blockDim = MAXB
    int sumD = (tid < NB) ? totals[tid] : 0;
    sc[tid] = sumD;
    __syncthreads();
    for (int off = 1; off < MAXB; off <<= 1) {
        int v = (tid >= off) ? sc[tid - off] : 0;
        __syncthreads();
        sc[tid] += v;
        __syncthreads();
    }
    if (tid < NB) bbD[tid] = sc[tid] - sumD;
    if (tid == 0) { bbD[NB] = E; row_ptr[N] = E; }
    __syncthreads();
    int sumS = (tid < NB) ? totals[NB + tid] : 0;
    sc[tid] = sumS;
    __syncthreads();
    for (int off = 1; off < MAXB; off <<= 1) {
        int v = (tid >= off) ? sc[tid - off] : 0;
        __syncthreads();
        sc[tid] += v;
        __syncthreads();
    }
    if (tid < NB) bbS[tid] = sc[tid] - sumS;
    if (tid == 0) bbS[NB] = E;
}

// K3: single-pass scatter, zero global atomics (deterministic per-block bases).
__global__ void scatter_kernel(const int* __restrict__ idx, int E, int NB,
                               const int* __restrict__ partial,
                               const int* __restrict__ bbD,
                               const int* __restrict__ bbS,
                               int* __restrict__ entry_pool,
                               int* __restrict__ key_pool) {
    __shared__ int cb[2 * MAXB];
    __shared__ int h[2 * MAXB];
    int tid = threadIdx.x;
    int b = blockIdx.x;
    for (int i = tid; i < 2 * NB; i += blockDim.x) {
        int base = (i < NB) ? bbD[i] : bbS[i - NB];
        cb[i] = base + partial[(size_t)i * NBLK + b];
        h[i] = 0;
    }
    __syncthreads();
    int stride = gridDim.x * blockDim.x;
    for (int e = b * blockDim.x + tid; e < E; e += stride) {
        int dst = idx[e], src = idx[E + e];
        int qd = dst >> 8;
        int sl = atomicAdd(&h[qd], 1);
        entry_pool[cb[qd] + sl] = (src << 8) | (dst & 255);
        int qs = NB + (src >> 8);
        int sl2 = atomicAdd(&h[qs], 1);
        key_pool[cb[qs] + sl2] = src;
    }
}

// K4: per src-bucket count -> srcfac[n] = rsqrt(max(deg_src,1)).
__global__ void srccount_kernel(const int* __restrict__ key_pool,
                                const int* __restrict__ bbS,
                                float* __restrict__ srcfac, int N) {
    __shared__ int cnt[256];
    int q = blockIdx.x, tid = threadIdx.x;  // 512 threads
    if (tid < 256) cnt[tid] = 0;
    __syncthreads();
    int s0 = bbS[q], s1 = bbS[q + 1];
    for (int j = s0 + tid; j < s1; j += 512)
        atomicAdd(&cnt[key_pool[j] & 255], 1);
    __syncthreads();
    int node = q * 256 + tid;
    if (tid < 256 && node < N)
        srcfac[node] = rsqrtf(fmaxf((float)cnt[tid], 1.0f));
}

// K5: per dst-bucket: count, scan -> row_ptr; place src into CSR slots.
__global__ void order_kernel(const int* __restrict__ entry_pool,
                             const int* __restrict__ bbD,
                             int* __restrict__ row_ptr,
                             int* __restrict__ csr, int N) {
    __shared__ int cnt[256];
    __shared__ int pref[256];
    __shared__ int lcur[256];
    int q = blockIdx.x, tid = threadIdx.x;  // 512 threads
    if (tid < 256) cnt[tid] = 0;
    __syncthreads();
    int s0 = bbD[q], s1 = bbD[q + 1];
    for (int j = s0 + tid; j < s1; j += 512)
        atomicAdd(&cnt[entry_pool[j] & 255], 1);
    __syncthreads();
    int v = 0;
    if (tid < 256) { v = cnt[tid]; pref[tid] = v; }
    __syncthreads();
    for (int off = 1; off < 256; off <<= 1) {
        int u = (tid < 256 && tid >= off) ? pref[tid - off] : 0;
        __syncthreads();
        if (tid < 256) pref[tid] += u;
        __syncthreads();
    }
    if (tid < 256) {
        int excl = pref[tid] - v;
        int node = q * 256 + tid;
        if (node < N) row_ptr[node] = s0 + excl;
        lcur[tid] = 0;
        pref[tid] = excl;
    }
    __syncthreads();
    for (int j = s0 + tid; j < s1; j += 512) {
        int ent = entry_pool[j];
        int dl = ent & 255;
        int sl = atomicAdd(&lcur[dl], 1);
        csr[s0 + pref[dl] + sl] = ent >> 8;
    }
}

__device__ __forceinline__ unsigned short bfbits(float f) {
    __hip_bfloat16 h = __float2bfloat16(f);
    return *reinterpret_cast<unsigned short*>(&h);
}

// y'[n][d] = bf16( srcfac[n] * sum_k x[n][k] * W[d][k] )   (R4-R6 verified)
__global__ void proj_kernel(const float* __restrict__ x,
                            const float* __restrict__ W,
                            const float* __restrict__ srcfac,
                            unsigned short* __restrict__ y, int N) {
    __shared__ float Wt[64 * 68];
    int tid = threadIdx.x;
    for (int i = tid; i < 4096; i += 256) {
        int k = i & 63, dd = i >> 6;
        Wt[k * 68 + dd] = W[dd * 64 + k];
    }
    __syncthreads();

    int lane = tid & 63;
    int nl = lane >> 4;
    int g  = lane & 15;
    int wid = (blockIdx.x * blockDim.x + tid) >> 6;
    int nwaves = (gridDim.x * blockDim.x) >> 6;
    int ngrp = (N + 3) >> 2;

    for (int grp = wid; grp < ngrp; grp += nwaves) {
        int n = grp * 4 + nl;
        if (n >= N) continue;
        const float4* __restrict__ xr = (const float4*)(x + (long long)n * 64);
        float s = srcfac[n];
        float a0 = 0.f, a1 = 0.f, a2 = 0.f, a3 = 0.f;
#pragma unroll
        for (int kc = 0; kc < 16; ++kc) {
            float4 xv = xr[kc];
            const float* wp = &Wt[(kc * 4) * 68 + 4 * g];
            float4 w0 = *(const float4*)(wp);
            float4 w1 = *(const float4*)(wp + 68);
            float4 w2 = *(const float4*)(wp + 136);
            float4 w3 = *(const float4*)(wp + 204);
            a0 = fmaf(xv.x, w0.x, a0); a1 = fmaf(xv.x, w0.y, a1);
            a2 = fmaf(xv.x, w0.z, a2); a3 = fmaf(xv.x, w0.w, a3);
            a0 = fmaf(xv.y, w1.x, a0); a1 = fmaf(xv.y, w1.y, a1);
            a2 = fmaf(xv.y, w1.z, a2); a3 = fmaf(xv.y, w1.w, a3);
            a0 = fmaf(xv.z, w2.x, a0); a1 = fmaf(xv.z, w2.y, a1);
            a2 = fmaf(xv.z, w2.z, a2); a3 = fmaf(xv.z, w2.w, a3);
            a0 = fmaf(xv.w, w3.x, a0); a1 = fmaf(xv.w, w3.y, a1);
            a2 = fmaf(xv.w, w3.z, a2); a3 = fmaf(xv.w, w3.w, a3);
        }
        ushort4 pk;
        pk.x = bfbits(a0 * s); pk.y = bfbits(a1 * s);
        pk.z = bfbits(a2 * s); pk.w = bfbits(a3 * s);
        *(ushort4*)(y + (long long)n * 64 + 4 * g) = pk;
    }
}

// R7 SpMM: wave per dst node, lane = feature. Scalar (wave-uniform) csr loads,
// per-edge 64x2B coalesced gather of one y row, shift+add, NO shuffles, loop
// runs exactly cnt edges. Unroll x4: 4 independent gathers in flight.
__global__ void spmm_kernel(const int* __restrict__ csr,
                            const int* __restrict__ row_ptr,
                            const unsigned short* __restrict__ y,
                            const float* __restrict__ b,
                            float* __restrict__ out, int N) {
    int t = blockIdx.x * blockDim.x + threadIdx.x;
    int n = __builtin_amdgcn_readfirstlane(t >> 6);  // wave-uniform node id
    if (n >= N) return;
    int lane = threadIdx.x & 63;

    int s0 = row_ptr[n];       // scalar loads (uniform address)
    int s1 = row_ptr[n + 1];
    const unsigned short* __restrict__ yl = y + lane;

    float a0 = 0.f, a1 = 0.f, a2 = 0.f, a3 = 0.f;
    int i = s0;
    for (; i + 4 <= s1; i += 4) {
        int c0 = csr[i];       // uniform -> s_load
        int c1 = csr[i + 1];
        int c2 = csr[i + 2];
        int c3 = csr[i + 3];
        unsigned v0 = yl[(unsigned)c0 << 6];
        unsigned v1 = yl[(unsigned)c1 << 6];
        unsigned v2 = yl[(unsigned)c2 << 6];
        unsigned v3 = yl[(unsigned)c3 << 6];
        a0 += __uint_as_float(v0 << 16);
        a1 += __uint_as_float(v1 << 16);
        a2 += __uint_as_float(v2 << 16);
        a3 += __uint_as_float(v3 << 16);
    }
    for (; i < s1; ++i) {
        unsigned v = yl[(unsigned)csr[i] << 6];
        a0 += __uint_as_float(v << 16);
    }
    int cnt = s1 - s0;
    float scl = rsqrtf(fmaxf((float)cnt, 1.0f));
    out[(size_t)n * 64 + lane] = (a0 + a1 + a2 + a3) * scl + b[lane];
}

extern "C" void kernel_launch(void* const* d_in, const int* in_sizes, int n_in,
                              void* d_out, int out_size, void* d_ws, size_t ws_size,
                              hipStream_t stream) {
    const float* x  = (const float*)d_in[0];
    const int*  idx = (const int*)d_in[1];
    const float* W  = (const float*)d_in[2];
    const float* b  = (const float*)d_in[3];
    float*      out = (float*)d_out;

    const int N = in_sizes[0] / 64;
    const int E = in_sizes[1] / 2;
    const int NB = (N + 255) >> 8;   // 256-node buckets

    int* ws = (int*)d_ws;
    size_t o = 0;
    int* partial    = ws + o; o += (size_t)2 * NB * NBLK;
    int* totals     = ws + o; o += 2 * NB;
    int* bbD        = ws + o; o += NB + 1;
    int* bbS        = ws + o; o += NB + 1;
    int* row_ptr    = ws + o; o += N + 1;
    float* srcfac   = (float*)(ws + o); o += N;
    int* entry_pool = ws + o; o += E;
    int* key_pool   = ws + o; o += E;
    int* csr        = key_pool;      // alias: key_pool dead after srccount
    o = (o + 63) & ~(size_t)63;
    unsigned short* y = (unsigned short*)(ws + o);

    hist_kernel<<<NBLK, 256, 0, stream>>>(idx, E, NB, partial);

    colprefix_kernel<<<(2 * NB + 255) / 256, 256, 0, stream>>>(partial, totals, NB);

    scan_kernel<<<1, MAXB, 0, stream>>>(totals, NB, E, N, bbD, bbS, row_ptr);

    scatter_kernel<<<NBLK, 256, 0, stream>>>(idx, E, NB, partial, bbD, bbS,
                                             entry_pool, key_pool);

    srccount_kernel<<<NB, 512, 0, stream>>>(key_pool, bbS, srcfac, N);

    order_kernel<<<NB, 512, 0, stream>>>(entry_pool, bbD, row_ptr, csr, N);

    proj_kernel<<<1600, 256, 0, stream>>>(x, W, srcfac, y, N);

    spmm_kernel<<<(N * 64 + 255) / 256, 256, 0, stream>>>(csr, row_ptr, y, b,
                                                          out, N);
}

// Round 8
// 211.244 us; speedup vs baseline: 1.1998x; 1.1998x over previous
//
#include <hip/hip_runtime.h>
#include <hip/hip_bf16.h>

// GCN 'attn' conv. R8: wave-parallel column-prefix (R7's hidden serial hog:
// 782 threads x 512 dependent loads), byte-wide src-key stream, spmm reverted
// to R6's dwordx4 form (R6/R7 A/B: spmm is bound by random 128B line service
// ~4.5 TB/s, not instruction mix).
//   out[n] = rsqrt(max(deg_dst[n],1)) * sum_{e: dst==n} y'[src_e] + b
//   y'[j]  = bf16( (x[j] @ W^T) * rsqrt(max(deg_src[j],1)) )
//
// ws: partial[2NB][NBLK] | totals[2NB] | bbD[NB+1] | bbS[NB+1] | row_ptr[N+1]
//   | srcfac[N] | entry_pool[E] (int) | key_pool[E] (bytes) | csr[E] (int)
//   | y_bf16[N*64]   (~30 MB). Every word written before read: no memset.

#define NBLK 512   // hist/scatter blocks: 2 per CU
#define MAXB 512   // max 256-node buckets per stream (N <= 131072)

// K1: per-block LDS histograms; bucket-major partial (contiguous columns)
__global__ void hist_kernel(const int* __restrict__ idx, int E, int NB,
                            int* __restrict__ partial) {
    __shared__ int h[2 * MAXB];
    int tid = threadIdx.x;
    for (int i = tid; i < 2 * NB; i += blockDim.x) h[i] = 0;
    __syncthreads();
    int stride = gridDim.x * blockDim.x;
    for (int e = blockIdx.x * blockDim.x + tid; e < E; e += stride) {
        atomicAdd(&h[idx[e] >> 8], 1);            // dst bucket (LDS)
        atomicAdd(&h[NB + (idx[E + e] >> 8)], 1); // src bucket (LDS)
    }
    __syncthreads();
    for (int i = tid; i < 2 * NB; i += blockDim.x)
        partial[(size_t)i * NBLK + blockIdx.x] = h[i];
}

// K2a (R8): wave per column. Lane owns 8 contiguous ints (2 x int4), local
// exclusive prefix + 6-step shfl_up wave scan. In-place; totals out.
__global__ void colprefix_kernel(int* __restrict__ partial,
                                 int* __restrict__ totals, int NB) {
    int w = (blockIdx.x * blockDim.x + threadIdx.x) >> 6;
    int lane = threadIdx.x & 63;
    if (w >= 2 * NB) return;
    int* col = partial + (size_t)w * NBLK;       // 512 ints, 2KB-aligned
    int4 a = ((int4*)col)[lane * 2];
    int4 c = ((int4*)col)[lane * 2 + 1];
    int s0 = a.x, s1 = s0 + a.y, s2 = s1 + a.z, s3 = s2 + a.w;
    int s4 = s3 + c.x, s5 = s4 + c.y, s6 = s5 + c.z, s7 = s6 + c.w;
    int incl = s7;
#pragma unroll
    for (int off = 1; off < 64; off <<= 1) {
        int v = __shfl_up(incl, off, 64);
        if (lane >= off) incl += v;
    }
    int excl = incl - s7;
    int4 oa, oc;
    oa.x = excl;      oa.y = excl + s0; oa.z = excl + s1; oa.w = excl + s2;
    oc.x = excl + s3; oc.y = excl + s4; oc.z = excl + s5; oc.w = excl + s6;
    ((int4*)col)[lane * 2] = oa;
    ((int4*)col)[lane * 2 + 1] = oc;
    if (lane == 63) totals[w] = excl + s7;
}

// K2b: exclusive scans of bucket totals -> bbD, bbS.
__global__ void scan_kernel(const int* __restrict__ totals, int NB, int E, int N,
                            int* __restrict__ bbD, int* __restrict__ bbS,
                            int* __restrict__ row_ptr) {
    __shared__ int sc[MAXB];
    int tid = threadIdx.x;  // blockDim = MAXB
    int sumD = (tid < NB) ? totals[tid] : 0;
    sc[tid] = sumD;
    __syncthreads();
    for (int off = 1; off < MAXB; off <<= 1) {
        int v = (tid >= off) ? sc[tid - off] : 0;
        __syncthreads();
        sc[tid] += v;
        __syncthreads();
    }
    if (tid < NB) bbD[tid] = sc[tid] - sumD;
    if (tid == 0) { bbD[NB] = E; row_ptr[N] = E; }
    __syncthreads();
    int sumS = (tid < NB) ? totals[NB + tid] : 0;
    sc[tid] = sumS;
    __syncthreads();
    for (int off = 1; off < MAXB; off <<= 1) {
        int v = (tid >= off) ? sc[tid - off] : 0;
        __syncthreads();
        sc[tid] += v;
        __syncthreads();
    }
    if (tid < NB) bbS[tid] = sc[tid] - sumS;
    if (tid == 0) bbS[NB] = E;
}

// K3: single-pass scatter, zero global atomics. Src keys as BYTES (bucket is
// implicit; srccount needs only src&255) -> 4x less scattered write traffic.
__global__ void scatter_kernel(const int* __restrict__ idx, int E, int NB,
                               const int* __restrict__ partial,
                               const int* __restrict__ bbD,
                               const int* __restrict__ bbS,
                               int* __restrict__ entry_pool,
                               unsigned char* __restrict__ key_pool) {
    __shared__ int cb[2 * MAXB];
    __shared__ int h[2 * MAXB];
    int tid = threadIdx.x;
    int b = blockIdx.x;
    for (int i = tid; i < 2 * NB; i += blockDim.x) {
        int base = (i < NB) ? bbD[i] : bbS[i - NB];
        cb[i] = base + partial[(size_t)i * NBLK + b];
        h[i] = 0;
    }
    __syncthreads();
    int stride = gridDim.x * blockDim.x;
    for (int e = b * blockDim.x + tid; e < E; e += stride) {
        int dst = idx[e], src = idx[E + e];
        int qd = dst >> 8;
        int sl = atomicAdd(&h[qd], 1);
        entry_pool[cb[qd] + sl] = (src << 8) | (dst & 255);
        int qs = NB + (src >> 8);
        int sl2 = atomicAdd(&h[qs], 1);
        key_pool[cb[qs] + sl2] = (unsigned char)(src & 255);
    }
}

// K4: per src-bucket count -> srcfac[n] = rsqrt(max(deg_src,1)).
__global__ void srccount_kernel(const unsigned char* __restrict__ key_pool,
                                const int* __restrict__ bbS,
                                float* __restrict__ srcfac, int N) {
    __shared__ int cnt[256];
    int q = blockIdx.x, tid = threadIdx.x;  // 512 threads
    if (tid < 256) cnt[tid] = 0;
    __syncthreads();
    int s0 = bbS[q], s1 = bbS[q + 1];
    for (int j = s0 + tid; j < s1; j += 512)
        atomicAdd(&cnt[key_pool[j]], 1);
    __syncthreads();
    int node = q * 256 + tid;
    if (tid < 256 && node < N)
        srcfac[node] = rsqrtf(fmaxf((float)cnt[tid], 1.0f));
}

// K5: per dst-bucket: count, scan -> row_ptr; place src into CSR slots.
__global__ void order_kernel(const int* __restrict__ entry_pool,
                             const int* __restrict__ bbD,
                             int* __restrict__ row_ptr,
                             int* __restrict__ csr, int N) {
    __shared__ int cnt[256];
    __shared__ int pref[256];
    __shared__ int lcur[256];
    int q = blockIdx.x, tid = threadIdx.x;  // 512 threads
    if (tid < 256) cnt[tid] = 0;
    __syncthreads();
    int s0 = bbD[q], s1 = bbD[q + 1];
    for (int j = s0 + tid; j < s1; j += 512)
        atomicAdd(&cnt[entry_pool[j] & 255], 1);
    __syncthreads();
    int v = 0;
    if (tid < 256) { v = cnt[tid]; pref[tid] = v; }
    __syncthreads();
    for (int off = 1; off < 256; off <<= 1) {
        int u = (tid < 256 && tid >= off) ? pref[tid - off] : 0;
        __syncthreads();
        if (tid < 256) pref[tid] += u;
        __syncthreads();
    }
    if (tid < 256) {
        int excl = pref[tid] - v;
        int node = q * 256 + tid;
        if (node < N) row_ptr[node] = s0 + excl;
        lcur[tid] = 0;
        pref[tid] = excl;
    }
    __syncthreads();
    for (int j = s0 + tid; j < s1; j += 512) {
        int ent = entry_pool[j];
        int dl = ent & 255;
        int sl = atomicAdd(&lcur[dl], 1);
        csr[s0 + pref[dl] + sl] = ent >> 8;
    }
}

__device__ __forceinline__ unsigned short bfbits(float f) {
    __hip_bfloat16 h = __float2bfloat16(f);
    return *reinterpret_cast<unsigned short*>(&h);
}

// y'[n][d] = bf16( srcfac[n] * sum_k x[n][k] * W[d][k] )   (R4-R7 verified)
__global__ void proj_kernel(const float* __restrict__ x,
                            const float* __restrict__ W,
                            const float* __restrict__ srcfac,
                            unsigned short* __restrict__ y, int N) {
    __shared__ float Wt[64 * 68];
    int tid = threadIdx.x;
    for (int i = tid; i < 4096; i += 256) {
        int k = i & 63, dd = i >> 6;
        Wt[k * 68 + dd] = W[dd * 64 + k];
    }
    __syncthreads();

    int lane = tid & 63;
    int nl = lane >> 4;
    int g  = lane & 15;
    int wid = (blockIdx.x * blockDim.x + tid) >> 6;
    int nwaves = (gridDim.x * blockDim.x) >> 6;
    int ngrp = (N + 3) >> 2;

    for (int grp = wid; grp < ngrp; grp += nwaves) {
        int n = grp * 4 + nl;
        if (n >= N) continue;
        const float4* __restrict__ xr = (const float4*)(x + (long long)n * 64);
        float s = srcfac[n];
        float a0 = 0.f, a1 = 0.f, a2 = 0.f, a3 = 0.f;
#pragma unroll
        for (int kc = 0; kc < 16; ++kc) {
            float4 xv = xr[kc];
            const float* wp = &Wt[(kc * 4) * 68 + 4 * g];
            float4 w0 = *(const float4*)(wp);
            float4 w1 = *(const float4*)(wp + 68);
            float4 w2 = *(const float4*)(wp + 136);
            float4 w3 = *(const float4*)(wp + 204);
            a0 = fmaf(xv.x, w0.x, a0); a1 = fmaf(xv.x, w0.y, a1);
            a2 = fmaf(xv.x, w0.z, a2); a3 = fmaf(xv.x, w0.w, a3);
            a0 = fmaf(xv.y, w1.x, a0); a1 = fmaf(xv.y, w1.y, a1);
            a2 = fmaf(xv.y, w1.z, a2); a3 = fmaf(xv.y, w1.w, a3);
            a0 = fmaf(xv.z, w2.x, a0); a1 = fmaf(xv.z, w2.y, a1);
            a2 = fmaf(xv.z, w2.z, a2); a3 = fmaf(xv.z, w2.w, a3);
            a0 = fmaf(xv.w, w3.x, a0); a1 = fmaf(xv.w, w3.y, a1);
            a2 = fmaf(xv.w, w3.z, a2); a3 = fmaf(xv.w, w3.w, a3);
        }
        ushort4 pk;
        pk.x = bfbits(a0 * s); pk.y = bfbits(a1 * s);
        pk.z = bfbits(a2 * s); pk.w = bfbits(a3 * s);
        *(ushort4*)(y + (long long)n * 64 + 4 * g) = pk;
    }
}

// SpMM (R6 form — proven 45.4 us; bound by random 128B line service).
// Wave per dst node; lane = eg*8+h: 8 edges/wave-instr via dwordx4, unroll x2.
__global__ void spmm_kernel(const int* __restrict__ csr,
                            const int* __restrict__ row_ptr,
                            const unsigned short* __restrict__ y,
                            const float* __restrict__ b,
                            float* __restrict__ out, int N) {
    long long t = (long long)blockIdx.x * blockDim.x + threadIdx.x;
    int n = (int)(t >> 6);
    if (n >= N) return;
    int lane = (int)(t & 63);
    int eg = lane >> 3;
    int h  = lane & 7;

    int s0 = row_ptr[n];
    int cnt = row_ptr[n + 1] - s0;

    float acc[8];
#pragma unroll
    for (int j = 0; j < 8; ++j) acc[j] = 0.f;

    for (int i = 0; i < cnt; i += 16) {
        int e0 = i + eg, e1 = i + 8 + eg;
        float m0 = (e0 < cnt) ? 1.f : 0.f;
        float m1 = (e1 < cnt) ? 1.f : 0.f;
        int c0 = (e0 < cnt) ? csr[s0 + e0] : 0;
        int c1 = (e1 < cnt) ? csr[s0 + e1] : 0;
        uint4 r0 = ((const uint4*)(y + (long long)c0 * 64))[h];
        uint4 r1 = ((const uint4*)(y + (long long)c1 * 64))[h];
#pragma unroll
        for (int q = 0; q < 2; ++q) {
            uint4 r = q ? r1 : r0;
            float m = q ? m1 : m0;
            unsigned int ws4[4] = {r.x, r.y, r.z, r.w};
#pragma unroll
            for (int c = 0; c < 4; ++c) {
                float lo = __uint_as_float(ws4[c] << 16);
                float hi = __uint_as_float(ws4[c] & 0xffff0000u);
                acc[2 * c]     = fmaf(m, lo, acc[2 * c]);
                acc[2 * c + 1] = fmaf(m, hi, acc[2 * c + 1]);
            }
        }
    }
#pragma unroll
    for (int m = 8; m < 64; m <<= 1)
#pragma unroll
        for (int j = 0; j < 8; ++j) acc[j] += __shfl_xor(acc[j], m, 64);

    if (eg == 0) {
        float scl = rsqrtf(fmaxf((float)cnt, 1.0f));
        float4 b0 = ((const float4*)b)[h * 2];
        float4 b1 = ((const float4*)b)[h * 2 + 1];
        float4 o0 = {acc[0] * scl + b0.x, acc[1] * scl + b0.y,
                     acc[2] * scl + b0.z, acc[3] * scl + b0.w};
        float4 o1 = {acc[4] * scl + b1.x, acc[5] * scl + b1.y,
                     acc[6] * scl + b1.z, acc[7] * scl + b1.w};
        float4* op = (float4*)(out + (long long)n * 64);
        op[h * 2] = o0;
        op[h * 2 + 1] = o1;
    }
}

extern "C" void kernel_launch(void* const* d_in, const int* in_sizes, int n_in,
                              void* d_out, int out_size, void* d_ws, size_t ws_size,
                              hipStream_t stream) {
    const float* x  = (const float*)d_in[0];
    const int*  idx = (const int*)d_in[1];
    const float* W  = (const float*)d_in[2];
    const float* b  = (const float*)d_in[3];
    float*      out = (float*)d_out;

    const int N = in_sizes[0] / 64;
    const int E = in_sizes[1] / 2;
    const int NB = (N + 255) >> 8;   // 256-node buckets

    int* ws = (int*)d_ws;
    size_t o = 0;
    int* partial    = ws + o; o += (size_t)2 * NB * NBLK;
    int* totals     = ws + o; o += 2 * NB;
    int* bbD        = ws + o; o += NB + 1;
    int* bbS        = ws + o; o += NB + 1;
    int* row_ptr    = ws + o; o += N + 1;
    float* srcfac   = (float*)(ws + o); o += N;
    int* entry_pool = ws + o; o += E;
    unsigned char* key_pool = (unsigned char*)(ws + o); o += (E + 3) / 4;
    o = (o + 15) & ~(size_t)15;
    int* csr        = ws + o; o += E;
    o = (o + 63) & ~(size_t)63;
    unsigned short* y = (unsigned short*)(ws + o);

    hist_kernel<<<NBLK, 256, 0, stream>>>(idx, E, NB, partial);

    colprefix_kernel<<<(2 * NB * 64 + 255) / 256, 256, 0, stream>>>(partial,
                                                                    totals, NB);

    scan_kernel<<<1, MAXB, 0, stream>>>(totals, NB, E, N, bbD, bbS, row_ptr);

    scatter_kernel<<<NBLK, 256, 0, stream>>>(idx, E, NB, partial, bbD, bbS,
                                             entry_pool, key_pool);

    srccount_kernel<<<NB, 512, 0, stream>>>(key_pool, bbS, srcfac, N);

    order_kernel<<<NB, 512, 0, stream>>>(entry_pool, bbD, row_ptr, csr, N);

    proj_kernel<<<1600, 256, 0, stream>>>(x, W, srcfac, y, N);

    spmm_kernel<<<(N * 64 + 255) / 256, 256, 0, stream>>>(csr, row_ptr, y, b,
                                                          out, N);
}

// Round 9
// 206.153 us; speedup vs baseline: 1.2294x; 1.0247x over previous
//
#include <hip/hip_runtime.h>
#include <hip/hip_bf16.h>

// GCN 'attn' conv. R9: MFMA projection + NBLK=1024 (hist/scatter occupancy)
// + merged srccount/order. spmm kept in R6 form (R6/R7 A/B proved it's at the
// random-128B-line service floor ~46 us).
//   out[n] = rsqrt(max(deg_dst[n],1)) * sum_{e: dst==n} y'[src_e] + b
//   y'[j]  = bf16( (x[j] @ W^T) * rsqrt(max(deg_src[j],1)) )
//
// ws: partial[2NB][NBLK] | totals[2NB] | bbD[NB+1] | bbS[NB+1] | row_ptr[N+1]
//   | srcfac[N] | entry_pool[E] | key_pool[E bytes] | csr[E] | y_bf16[N*64]
// Every word written before read: no memset.

#define NBLK 1024  // hist/scatter blocks: 4 per CU
#define MAXB 512   // max 256-node buckets per stream (N <= 131072)

typedef __attribute__((ext_vector_type(8))) short bf16x8;  // MFMA A/B frag
typedef __attribute__((ext_vector_type(4))) float f32x4;   // MFMA C/D frag

__device__ __forceinline__ unsigned short bfbits(float f) {
    __hip_bfloat16 h = __float2bfloat16(f);
    return *reinterpret_cast<unsigned short*>(&h);
}

// K1: per-block LDS histograms; bucket-major partial (contiguous columns)
__global__ void hist_kernel(const int* __restrict__ idx, int E, int NB,
                            int* __restrict__ partial) {
    __shared__ int h[2 * MAXB];
    int tid = threadIdx.x;
    for (int i = tid; i < 2 * NB; i += blockDim.x) h[i] = 0;
    __syncthreads();
    int stride = gridDim.x * blockDim.x;
    for (int e = blockIdx.x * blockDim.x + tid; e < E; e += stride) {
        atomicAdd(&h[idx[e] >> 8], 1);            // dst bucket (LDS)
        atomicAdd(&h[NB + (idx[E + e] >> 8)], 1); // src bucket (LDS)
    }
    __syncthreads();
    for (int i = tid; i < 2 * NB; i += blockDim.x)
        partial[(size_t)i * NBLK + blockIdx.x] = h[i];
}

// K2a: wave per column (1024 ints); lane owns 16 contiguous ints (4 x int4).
__global__ void colprefix_kernel(int* __restrict__ partial,
                                 int* __restrict__ totals, int NB) {
    int w = (blockIdx.x * blockDim.x + threadIdx.x) >> 6;
    int lane = threadIdx.x & 63;
    if (w >= 2 * NB) return;
    int4* cp = (int4*)(partial + (size_t)w * NBLK);
    int a[16];
#pragma unroll
    for (int i = 0; i < 4; ++i) {
        int4 t = cp[lane * 4 + i];
        a[4 * i] = t.x; a[4 * i + 1] = t.y; a[4 * i + 2] = t.z; a[4 * i + 3] = t.w;
    }
    int run = 0;
#pragma unroll
    for (int i = 0; i < 16; ++i) { int t = a[i]; a[i] = run; run += t; }
    int incl = run;
#pragma unroll
    for (int off = 1; off < 64; off <<= 1) {
        int v = __shfl_up(incl, off, 64);
        if (lane >= off) incl += v;
    }
    int excl = incl - run;
#pragma unroll
    for (int i = 0; i < 16; ++i) a[i] += excl;
#pragma unroll
    for (int i = 0; i < 4; ++i) {
        int4 t = {a[4 * i], a[4 * i + 1], a[4 * i + 2], a[4 * i + 3]};
        cp[lane * 4 + i] = t;
    }
    if (lane == 63) totals[w] = incl;
}

// K2b: exclusive scans of bucket totals -> bbD, bbS.
__global__ void scan_kernel(const int* __restrict__ totals, int NB, int E, int N,
                            int* __restrict__ bbD, int* __restrict__ bbS,
                            int* __restrict__ row_ptr) {
    __shared__ int sc[MAXB];
    int tid = threadIdx.x;  // blockDim = MAXB
    int sumD = (tid < NB) ? totals[tid] : 0;
    sc[tid] = sumD;
    __syncthreads();
    for (int off = 1; off < MAXB; off <<= 1) {
        int v = (tid >= off) ? sc[tid - off] : 0;
        __syncthreads();
        sc[tid] += v;
        __syncthreads();
    }
    if (tid < NB) bbD[tid] = sc[tid] - sumD;
    if (tid == 0) { bbD[NB] = E; row_ptr[N] = E; }
    __syncthreads();
    int sumS = (tid < NB) ? totals[NB + tid] : 0;
    sc[tid] = sumS;
    __syncthreads();
    for (int off = 1; off < MAXB; off <<= 1) {
        int v = (tid >= off) ? sc[tid - off] : 0;
        __syncthreads();
        sc[tid] += v;
        __syncthreads();
    }
    if (tid < NB) bbS[tid] = sc[tid] - sumS;
    if (tid == 0) bbS[NB] = E;
}

// K3: single-pass scatter, zero global atomics (deterministic per-block bases).
__global__ void scatter_kernel(const int* __restrict__ idx, int E, int NB,
                               const int* __restrict__ partial,
                               const int* __restrict__ bbD,
                               const int* __restrict__ bbS,
                               int* __restrict__ entry_pool,
                               unsigned char* __restrict__ key_pool) {
    __shared__ int cb[2 * MAXB];
    __shared__ int h[2 * MAXB];
    int tid = threadIdx.x;
    int b = blockIdx.x;
    for (int i = tid; i < 2 * NB; i += blockDim.x) {
        int base = (i < NB) ? bbD[i] : bbS[i - NB];
        cb[i] = base + partial[(size_t)i * NBLK + b];
        h[i] = 0;
    }
    __syncthreads();
    int stride = gridDim.x * blockDim.x;
    for (int e = b * blockDim.x + tid; e < E; e += stride) {
        int dst = idx[e], src = idx[E + e];
        int qd = dst >> 8;
        int sl = atomicAdd(&h[qd], 1);
        entry_pool[cb[qd] + sl] = (src << 8) | (dst & 255);
        int qs = NB + (src >> 8);
        int sl2 = atomicAdd(&h[qs], 1);
        key_pool[cb[qs] + sl2] = (unsigned char)(src & 255);
    }
}

// K4 (merged): blocks [0,NB) do order (row_ptr+csr); [NB,2NB) do srccount.
__global__ void srcorder_kernel(const int* __restrict__ entry_pool,
                                const unsigned char* __restrict__ key_pool,
                                const int* __restrict__ bbD,
                                const int* __restrict__ bbS,
                                int* __restrict__ row_ptr,
                                int* __restrict__ csr,
                                float* __restrict__ srcfac, int N, int NB) {
    __shared__ int cnt[256];
    __shared__ int pref[256];
    __shared__ int lcur[256];
    int tid = threadIdx.x;  // 512 threads
    if (blockIdx.x >= NB) {
        // ---- srccount for bucket q ----
        int q = blockIdx.x - NB;
        if (tid < 256) cnt[tid] = 0;
        __syncthreads();
        int s0 = bbS[q], s1 = bbS[q + 1];
        for (int j = s0 + tid; j < s1; j += 512)
            atomicAdd(&cnt[key_pool[j]], 1);
        __syncthreads();
        int node = q * 256 + tid;
        if (tid < 256 && node < N)
            srcfac[node] = rsqrtf(fmaxf((float)cnt[tid], 1.0f));
        return;
    }
    // ---- order for bucket q ----
    int q = blockIdx.x;
    if (tid < 256) cnt[tid] = 0;
    __syncthreads();
    int s0 = bbD[q], s1 = bbD[q + 1];
    for (int j = s0 + tid; j < s1; j += 512)
        atomicAdd(&cnt[entry_pool[j] & 255], 1);
    __syncthreads();
    int v = 0;
    if (tid < 256) { v = cnt[tid]; pref[tid] = v; }
    __syncthreads();
    for (int off = 1; off < 256; off <<= 1) {
        int u = (tid < 256 && tid >= off) ? pref[tid - off] : 0;
        __syncthreads();
        if (tid < 256) pref[tid] += u;
        __syncthreads();
    }
    if (tid < 256) {
        int excl = pref[tid] - v;
        int node = q * 256 + tid;
        if (node < N) row_ptr[node] = s0 + excl;
        lcur[tid] = 0;
        pref[tid] = excl;
    }
    __syncthreads();
    for (int j = s0 + tid; j < s1; j += 512) {
        int ent = entry_pool[j];
        int dl = ent & 255;
        int sl = atomicAdd(&lcur[dl], 1);
        csr[s0 + pref[dl] + sl] = ent >> 8;
    }
}

// K5 (R9): MFMA projection. Wave = 16-node tile x 64 outputs.
// A[m][k]=x[nbase+m][k] (m=lane&15, k=(lane>>4)*8+j per kstep), B[k][n]=
// W[t*16+n][k] (W rows are contiguous in k). D: col=lane&15 (=output within
// tile), row=(lane>>4)*4+reg (=node offset). Layouts per m89/m91-verified map.
__global__ void proj_kernel(const float* __restrict__ x,
                            const float* __restrict__ W,
                            const float* __restrict__ srcfac,
                            unsigned short* __restrict__ y, int N) {
    int tid = threadIdx.x;
    int lane = tid & 63;
    int m = lane & 15;      // A: node-in-tile | B: output col | D: col
    int q = lane >> 4;      // k-block selector / D row group

    // Hoisted B-frags: bf[t][s] elem j = bf16(W[(t*16+m)][s*32+q*8+j])
    bf16x8 bf[4][2];
#pragma unroll
    for (int t = 0; t < 4; ++t)
#pragma unroll
        for (int s = 0; s < 2; ++s) {
            const float* wp = W + (t * 16 + m) * 64 + s * 32 + q * 8;
            float4 lo = *(const float4*)wp;
            float4 hi = *(const float4*)(wp + 4);
            bf16x8 f;
            f[0] = (short)bfbits(lo.x); f[1] = (short)bfbits(lo.y);
            f[2] = (short)bfbits(lo.z); f[3] = (short)bfbits(lo.w);
            f[4] = (short)bfbits(hi.x); f[5] = (short)bfbits(hi.y);
            f[6] = (short)bfbits(hi.z); f[7] = (short)bfbits(hi.w);
            bf[t][s] = f;
        }

    int wid = (blockIdx.x * blockDim.x + tid) >> 6;
    int nwaves = (gridDim.x * blockDim.x) >> 6;
    int ntiles = (N + 15) >> 4;

    for (int tile = wid; tile < ntiles; tile += nwaves) {
        int nbase = tile << 4;
        int nrow = nbase + m;
        const float* xp = x + (size_t)(nrow < N ? nrow : N - 1) * 64 + q * 8;
        bf16x8 af[2];
#pragma unroll
        for (int s = 0; s < 2; ++s) {
            float4 lo = *(const float4*)(xp + s * 32);
            float4 hi = *(const float4*)(xp + s * 32 + 4);
            bf16x8 f;
            f[0] = (short)bfbits(lo.x); f[1] = (short)bfbits(lo.y);
            f[2] = (short)bfbits(lo.z); f[3] = (short)bfbits(lo.w);
            f[4] = (short)bfbits(hi.x); f[5] = (short)bfbits(hi.y);
            f[6] = (short)bfbits(hi.z); f[7] = (short)bfbits(hi.w);
            af[s] = f;
        }
        f32x4 acc[4];
#pragma unroll
        for (int t = 0; t < 4; ++t) {
            f32x4 c = {0.f, 0.f, 0.f, 0.f};
            c = __builtin_amdgcn_mfma_f32_16x16x32_bf16(af[0], bf[t][0], c, 0, 0, 0);
            c = __builtin_amdgcn_mfma_f32_16x16x32_bf16(af[1], bf[t][1], c, 0, 0, 0);
            acc[t] = c;
        }
#pragma unroll
        for (int r = 0; r < 4; ++r) {
            int node = nbase + q * 4 + r;
            if (node < N) {
                float sf = srcfac[node];
#pragma unroll
                for (int t = 0; t < 4; ++t)
                    y[(size_t)node * 64 + t * 16 + m] = bfbits(acc[t][r] * sf);
            }
        }
    }
}

// SpMM (R6 form — at the random-128B-line service floor).
__global__ void spmm_kernel(const int* __restrict__ csr,
                            const int* __restrict__ row_ptr,
                            const unsigned short* __restrict__ y,
                            const float* __restrict__ b,
                            float* __restrict__ out, int N) {
    long long t = (long long)blockIdx.x * blockDim.x + threadIdx.x;
    int n = (int)(t >> 6);
    if (n >= N) return;
    int lane = (int)(t & 63);
    int eg = lane >> 3;
    int h  = lane & 7;

    int s0 = row_ptr[n];
    int cnt = row_ptr[n + 1] - s0;

    float acc[8];
#pragma unroll
    for (int j = 0; j < 8; ++j) acc[j] = 0.f;

    for (int i = 0; i < cnt; i += 16) {
        int e0 = i + eg, e1 = i + 8 + eg;
        float m0 = (e0 < cnt) ? 1.f : 0.f;
        float m1 = (e1 < cnt) ? 1.f : 0.f;
        int c0 = (e0 < cnt) ? csr[s0 + e0] : 0;
        int c1 = (e1 < cnt) ? csr[s0 + e1] : 0;
        uint4 r0 = ((const uint4*)(y + (long long)c0 * 64))[h];
        uint4 r1 = ((const uint4*)(y + (long long)c1 * 64))[h];
#pragma unroll
        for (int qq = 0; qq < 2; ++qq) {
            uint4 r = qq ? r1 : r0;
            float mm = qq ? m1 : m0;
            unsigned int ws4[4] = {r.x, r.y, r.z, r.w};
#pragma unroll
            for (int c = 0; c < 4; ++c) {
                float lo = __uint_as_float(ws4[c] << 16);
                float hi = __uint_as_float(ws4[c] & 0xffff0000u);
                acc[2 * c]     = fmaf(mm, lo, acc[2 * c]);
                acc[2 * c + 1] = fmaf(mm, hi, acc[2 * c + 1]);
            }
        }
    }
#pragma unroll
    for (int mk = 8; mk < 64; mk <<= 1)
#pragma unroll
        for (int j = 0; j < 8; ++j) acc[j] += __shfl_xor(acc[j], mk, 64);

    if (eg == 0) {
        float scl = rsqrtf(fmaxf((float)cnt, 1.0f));
        float4 b0 = ((const float4*)b)[h * 2];
        float4 b1 = ((const float4*)b)[h * 2 + 1];
        float4 o0 = {acc[0] * scl + b0.x, acc[1] * scl + b0.y,
                     acc[2] * scl + b0.z, acc[3] * scl + b0.w};
        float4 o1 = {acc[4] * scl + b1.x, acc[5] * scl + b1.y,
                     acc[6] * scl + b1.z, acc[7] * scl + b1.w};
        float4* op = (float4*)(out + (long long)n * 64);
        op[h * 2] = o0;
        op[h * 2 + 1] = o1;
    }
}

extern "C" void kernel_launch(void* const* d_in, const int* in_sizes, int n_in,
                              void* d_out, int out_size, void* d_ws, size_t ws_size,
                              hipStream_t stream) {
    const float* x  = (const float*)d_in[0];
    const int*  idx = (const int*)d_in[1];
    const float* W  = (const float*)d_in[2];
    const float* b  = (const float*)d_in[3];
    float*      out = (float*)d_out;

    const int N = in_sizes[0] / 64;
    const int E = in_sizes[1] / 2;
    const int NB = (N + 255) >> 8;   // 256-node buckets

    int* ws = (int*)d_ws;
    size_t o = 0;
    int* partial    = ws + o; o += (size_t)2 * NB * NBLK;
    int* totals     = ws + o; o += 2 * NB;
    int* bbD        = ws + o; o += NB + 1;
    int* bbS        = ws + o; o += NB + 1;
    int* row_ptr    = ws + o; o += N + 1;
    float* srcfac   = (float*)(ws + o); o += N;
    int* entry_pool = ws + o; o += E;
    unsigned char* key_pool = (unsigned char*)(ws + o); o += (E + 3) / 4;
    o = (o + 15) & ~(size_t)15;
    int* csr        = ws + o; o += E;
    o = (o + 63) & ~(size_t)63;
    unsigned short* y = (unsigned short*)(ws + o);

    hist_kernel<<<NBLK, 256, 0, stream>>>(idx, E, NB, partial);

    colprefix_kernel<<<(2 * NB * 64 + 255) / 256, 256, 0, stream>>>(partial,
                                                                    totals, NB);

    scan_kernel<<<1, MAXB, 0, stream>>>(totals, NB, E, N, bbD, bbS, row_ptr);

    scatter_kernel<<<NBLK, 256, 0, stream>>>(idx, E, NB, partial, bbD, bbS,
                                             entry_pool, key_pool);

    srcorder_kernel<<<2 * NB, 512, 0, stream>>>(entry_pool, key_pool, bbD, bbS,
                                                row_ptr, csr, srcfac, N, NB);

    proj_kernel<<<256, 256, 0, stream>>>(x, W, srcfac, y, N);

    spmm_kernel<<<(N * 64 + 255) / 256, 256, 0, stream>>>(csr, row_ptr, y, b,
                                                          out, N);
}

// Round 10
// 190.573 us; speedup vs baseline: 1.3299x; 1.0818x over previous
//
#include <hip/hip_runtime.h>
#include <hip/hip_bf16.h>

// GCN 'attn' conv. R10: 512-node buckets (full 32B write sectors), per-block
// LDS scan of bucket totals (scan_kernel removed), srccount merged into the
// MFMA projection, int4 edge loads. spmm kept in R6 form: R6/R7/R9 showed it
// pinned at the random-128B-line service floor (~46 us, FETCH 81MB).
//   out[n] = rsqrt(max(deg_dst[n],1)) * sum_{e: dst==n} y'[src_e] + b
//   y'[j]  = bf16( (x[j] @ W^T) * rsqrt(max(deg_src[j],1)) )
//
// ws: partial[2NB][NBLK] | totals[2NB] | row_ptr[N+1] | entry_pool[E] |
//     key_pool[E ushort] | csr[E] | y_bf16[N*64]  (~31 MB)
// Every word written before read: no memset.
// CRITICAL INVARIANT: hist and scatter must traverse edges with IDENTICAL
// (block,thread)->edge partitions (same grid, block dim, loop structure) so
// per-(block,bucket) counts match the deterministic write bases.

#define NBLK 1024   // hist/scatter blocks
#define BDIM 512    // hist/scatter block dim (partition identity!)
#define BSZ  512    // nodes per bucket
#define SCAP 512    // scan width: max 2NB  (N <= 131072 -> NB <= 256)

typedef __attribute__((ext_vector_type(8))) short bf16x8;  // MFMA A/B frag
typedef __attribute__((ext_vector_type(4))) float f32x4;   // MFMA C/D frag

__device__ __forceinline__ unsigned short bfbits(float f) {
    __hip_bfloat16 h = __float2bfloat16(f);
    return *reinterpret_cast<unsigned short*>(&h);
}

// K1: per-block LDS histograms over 512-node buckets; bucket-major partial.
__global__ void hist_kernel(const int* __restrict__ idx, int E, int NB,
                            int* __restrict__ partial) {
    __shared__ int h[SCAP];
    int tid = threadIdx.x;
    for (int i = tid; i < 2 * NB; i += BDIM) h[i] = 0;
    __syncthreads();
    int stride = gridDim.x * BDIM;
    int nv = (E & 3) ? 0 : (E >> 2);          // int4 path only if E%4==0
    const int4* d4 = (const int4*)idx;
    const int4* s4 = (const int4*)(idx + E);
    for (int v = blockIdx.x * BDIM + tid; v < nv; v += stride) {
        int4 d = d4[v], s = s4[v];
        atomicAdd(&h[d.x >> 9], 1); atomicAdd(&h[d.y >> 9], 1);
        atomicAdd(&h[d.z >> 9], 1); atomicAdd(&h[d.w >> 9], 1);
        atomicAdd(&h[NB + (s.x >> 9)], 1); atomicAdd(&h[NB + (s.y >> 9)], 1);
        atomicAdd(&h[NB + (s.z >> 9)], 1); atomicAdd(&h[NB + (s.w >> 9)], 1);
    }
    for (int e = nv * 4 + blockIdx.x * BDIM + tid; e < E; e += stride) {
        atomicAdd(&h[idx[e] >> 9], 1);
        atomicAdd(&h[NB + (idx[E + e] >> 9)], 1);
    }
    __syncthreads();
    for (int i = tid; i < 2 * NB; i += BDIM)
        partial[(size_t)i * NBLK + blockIdx.x] = h[i];
}

// K2: wave per column (NBLK=1024 ints, 16 per lane); in-place exclusive
// per-block offsets + totals. Also seeds row_ptr[N]=E.
__global__ void colprefix_kernel(int* __restrict__ partial,
                                 int* __restrict__ totals, int NB,
                                 int* __restrict__ row_ptr, int N, int E) {
    if (blockIdx.x == 0 && threadIdx.x == 0) row_ptr[N] = E;
    int w = (blockIdx.x * blockDim.x + threadIdx.x) >> 6;
    int lane = threadIdx.x & 63;
    if (w >= 2 * NB) return;
    int4* cp = (int4*)(partial + (size_t)w * NBLK);
    int a[16];
#pragma unroll
    for (int i = 0; i < 4; ++i) {
        int4 t = cp[lane * 4 + i];
        a[4 * i] = t.x; a[4 * i + 1] = t.y; a[4 * i + 2] = t.z; a[4 * i + 3] = t.w;
    }
    int run = 0;
#pragma unroll
    for (int i = 0; i < 16; ++i) { int t = a[i]; a[i] = run; run += t; }
    int incl = run;
#pragma unroll
    for (int off = 1; off < 64; off <<= 1) {
        int v = __shfl_up(incl, off, 64);
        if (lane >= off) incl += v;
    }
    int excl = incl - run;
#pragma unroll
    for (int i = 0; i < 16; ++i) a[i] += excl;
#pragma unroll
    for (int i = 0; i < 4; ++i) {
        int4 t = {a[4 * i], a[4 * i + 1], a[4 * i + 2], a[4 * i + 3]};
        cp[lane * 4 + i] = t;
    }
    if (lane == 63) totals[w] = incl;
}

// K3: single-pass scatter, zero global atomics. Bucket bases computed by an
// in-block LDS scan of totals (concat: dst stream [0,NB), src stream [NB,2NB),
// src bases shifted by -E to index key_pool).
__global__ void scatter_kernel(const int* __restrict__ idx, int E, int NB,
                               const int* __restrict__ partial,
                               const int* __restrict__ totals,
                               int* __restrict__ entry_pool,
                               unsigned short* __restrict__ key_pool) {
    __shared__ int sc[SCAP];
    __shared__ int cb[SCAP];
    __shared__ int h[SCAP];
    int tid = threadIdx.x;   // BDIM == SCAP == 512
    int b = blockIdx.x;
    int t = (tid < 2 * NB) ? totals[tid] : 0;
    sc[tid] = t;
    __syncthreads();
    for (int off = 1; off < SCAP; off <<= 1) {
        int u = (tid >= off) ? sc[tid - off] : 0;
        __syncthreads();
        sc[tid] += u;
        __syncthreads();
    }
    if (tid < 2 * NB) {
        int base = sc[tid] - t - ((tid >= NB) ? E : 0);
        cb[tid] = base + partial[(size_t)tid * NBLK + b];
    }
    h[tid] = 0;
    __syncthreads();
    int stride = gridDim.x * BDIM;
    int nv = (E & 3) ? 0 : (E >> 2);
    const int4* d4 = (const int4*)idx;
    const int4* s4 = (const int4*)(idx + E);
    for (int v = b * BDIM + tid; v < nv; v += stride) {
        int4 d = d4[v], s = s4[v];
        int dd[4] = {d.x, d.y, d.z, d.w};
        int ss[4] = {s.x, s.y, s.z, s.w};
#pragma unroll
        for (int k = 0; k < 4; ++k) {
            int dst = dd[k], src = ss[k];
            int qd = dst >> 9;
            int sl = atomicAdd(&h[qd], 1);
            entry_pool[cb[qd] + sl] = (src << 9) | (dst & 511);
            int qs = NB + (src >> 9);
            int sl2 = atomicAdd(&h[qs], 1);
            key_pool[cb[qs] + sl2] = (unsigned short)(src & 511);
        }
    }
    for (int e = nv * 4 + b * BDIM + tid; e < E; e += stride) {
        int dst = idx[e], src = idx[E + e];
        int qd = dst >> 9;
        int sl = atomicAdd(&h[qd], 1);
        entry_pool[cb[qd] + sl] = (src << 9) | (dst & 511);
        int qs = NB + (src >> 9);
        int sl2 = atomicAdd(&h[qs], 1);
        key_pool[cb[qs] + sl2] = (unsigned short)(src & 511);
    }
}

// K4: per dst-bucket order: count, scan -> row_ptr; place src into csr.
// 512 threads == BSZ: no guards.
__global__ void order_kernel(const int* __restrict__ entry_pool,
                             const int* __restrict__ totals,
                             int* __restrict__ row_ptr,
                             int* __restrict__ csr, int N, int NB) {
    __shared__ int sc[SCAP];
    __shared__ int cnt[BSZ];
    __shared__ int pref[BSZ];
    __shared__ int lcur[BSZ];
    int tid = threadIdx.x;   // 512
    int q = blockIdx.x;
    int t = (tid < NB) ? totals[tid] : 0;   // dst stream only
    sc[tid] = t;
    __syncthreads();
    for (int off = 1; off < SCAP; off <<= 1) {
        int u = (tid >= off) ? sc[tid - off] : 0;
        __syncthreads();
        sc[tid] += u;
        __syncthreads();
    }
    int cntD = totals[q];
    int s1 = sc[q];
    int s0 = s1 - cntD;
    cnt[tid] = 0;
    __syncthreads();
    for (int j = s0 + tid; j < s1; j += BSZ)
        atomicAdd(&cnt[entry_pool[j] & 511], 1);
    __syncthreads();
    int v = cnt[tid];
    pref[tid] = v;
    __syncthreads();
    for (int off = 1; off < BSZ; off <<= 1) {
        int u = (tid >= off) ? pref[tid - off] : 0;
        __syncthreads();
        pref[tid] += u;
        __syncthreads();
    }
    int excl = pref[tid] - v;
    int node = q * BSZ + tid;
    if (node < N) row_ptr[node] = s0 + excl;
    lcur[tid] = 0;
    pref[tid] = excl;
    __syncthreads();
    for (int j = s0 + tid; j < s1; j += BSZ) {
        int ent = entry_pool[j];
        int dl = ent & 511;
        int sl = atomicAdd(&lcur[dl], 1);
        csr[s0 + pref[dl] + sl] = ent >> 9;
    }
}

// K5: MFMA projection + fused srccount. Block = one src bucket (512 nodes),
// 1024 threads = 16 waves. Phase 1: count keys -> fac[] in LDS. Phase 2:
// y' = bf16(fac * x @ W^T), 32 16-node tiles, 2 per wave.
// MFMA layouts per R9 (numerically verified: absmax unchanged).
__global__ __launch_bounds__(1024) void proj_kernel(
        const float* __restrict__ x, const float* __restrict__ W,
        const unsigned short* __restrict__ key_pool,
        const int* __restrict__ totals,
        unsigned short* __restrict__ y, int N, int NB, int E) {
    __shared__ int sc[SCAP];
    __shared__ int cnt[BSZ];
    __shared__ float fac[BSZ];
    int tid = threadIdx.x;
    int q = blockIdx.x;
    int t = 0;
    if (tid < SCAP) { t = (tid < 2 * NB) ? totals[tid] : 0; sc[tid] = t; }
    __syncthreads();
    for (int off = 1; off < SCAP; off <<= 1) {
        int u = (tid < SCAP && tid >= off) ? sc[tid - off] : 0;
        __syncthreads();
        if (tid < SCAP) sc[tid] += u;
        __syncthreads();
    }
    int cntS = totals[NB + q];
    int s1 = sc[NB + q] - E;      // key_pool-relative end
    int s0 = s1 - cntS;
    if (tid < BSZ) cnt[tid] = 0;
    __syncthreads();
    for (int j = s0 + tid; j < s1; j += 1024)
        atomicAdd(&cnt[key_pool[j]], 1);
    __syncthreads();
    if (tid < BSZ) fac[tid] = rsqrtf(fmaxf((float)cnt[tid], 1.0f));
    __syncthreads();

    int wave = tid >> 6, lane = tid & 63;
    int m = lane & 15, q4 = lane >> 4;

    // Hoisted B-frags: bf[tb][s] elem j = bf16(W[tb*16+m][s*32+q4*8+j])
    bf16x8 bf[4][2];
#pragma unroll
    for (int tb = 0; tb < 4; ++tb)
#pragma unroll
        for (int s = 0; s < 2; ++s) {
            const float* wp = W + (tb * 16 + m) * 64 + s * 32 + q4 * 8;
            float4 lo = *(const float4*)wp;
            float4 hi = *(const float4*)(wp + 4);
            bf16x8 f;
            f[0] = (short)bfbits(lo.x); f[1] = (short)bfbits(lo.y);
            f[2] = (short)bfbits(lo.z); f[3] = (short)bfbits(lo.w);
            f[4] = (short)bfbits(hi.x); f[5] = (short)bfbits(hi.y);
            f[6] = (short)bfbits(hi.z); f[7] = (short)bfbits(hi.w);
            bf[tb][s] = f;
        }

    for (int tile = wave; tile < BSZ / 16; tile += 16) {   // 32 tiles, 2/wave
        int nbase = q * BSZ + tile * 16;
        if (nbase >= N) break;
        int nrow = nbase + m;
        const float* xp = x + (size_t)(nrow < N ? nrow : N - 1) * 64 + q4 * 8;
        bf16x8 af[2];
#pragma unroll
        for (int s = 0; s < 2; ++s) {
            float4 lo = *(const float4*)(xp + s * 32);
            float4 hi = *(const float4*)(xp + s * 32 + 4);
            bf16x8 f;
            f[0] = (short)bfbits(lo.x); f[1] = (short)bfbits(lo.y);
            f[2] = (short)bfbits(lo.z); f[3] = (short)bfbits(lo.w);
            f[4] = (short)bfbits(hi.x); f[5] = (short)bfbits(hi.y);
            f[6] = (short)bfbits(hi.z); f[7] = (short)bfbits(hi.w);
            af[s] = f;
        }
        f32x4 acc[4];
#pragma unroll
        for (int tb = 0; tb < 4; ++tb) {
            f32x4 c = {0.f, 0.f, 0.f, 0.f};
            c = __builtin_amdgcn_mfma_f32_16x16x32_bf16(af[0], bf[tb][0], c, 0, 0, 0);
            c = __builtin_amdgcn_mfma_f32_16x16x32_bf16(af[1], bf[tb][1], c, 0, 0, 0);
            acc[tb] = c;
        }
#pragma unroll
        for (int r = 0; r < 4; ++r) {
            int node = nbase + q4 * 4 + r;
            if (node < N) {
                float sf = fac[node - q * BSZ];
#pragma unroll
                for (int tb = 0; tb < 4; ++tb)
                    y[(size_t)node * 64 + tb * 16 + m] = bfbits(acc[tb][r] * sf);
            }
        }
    }
}

// K6: SpMM (R6 form — pinned at the random-128B-line service floor).
__global__ void spmm_kernel(const int* __restrict__ csr,
                            const int* __restrict__ row_ptr,
                            const unsigned short* __restrict__ y,
                            const float* __restrict__ b,
                            float* __restrict__ out, int N) {
    long long t = (long long)blockIdx.x * blockDim.x + threadIdx.x;
    int n = (int)(t >> 6);
    if (n >= N) return;
    int lane = (int)(t & 63);
    int eg = lane >> 3;
    int h  = lane & 7;

    int s0 = row_ptr[n];
    int cnt = row_ptr[n + 1] - s0;

    float acc[8];
#pragma unroll
    for (int j = 0; j < 8; ++j) acc[j] = 0.f;

    for (int i = 0; i < cnt; i += 16) {
        int e0 = i + eg, e1 = i + 8 + eg;
        float m0 = (e0 < cnt) ? 1.f : 0.f;
        float m1 = (e1 < cnt) ? 1.f : 0.f;
        int c0 = (e0 < cnt) ? csr[s0 + e0] : 0;
        int c1 = (e1 < cnt) ? csr[s0 + e1] : 0;
        uint4 r0 = ((const uint4*)(y + (long long)c0 * 64))[h];
        uint4 r1 = ((const uint4*)(y + (long long)c1 * 64))[h];
#pragma unroll
        for (int qq = 0; qq < 2; ++qq) {
            uint4 r = qq ? r1 : r0;
            float mm = qq ? m1 : m0;
            unsigned int ws4[4] = {r.x, r.y, r.z, r.w};
#pragma unroll
            for (int c = 0; c < 4; ++c) {
                float lo = __uint_as_float(ws4[c] << 16);
                float hi = __uint_as_float(ws4[c] & 0xffff0000u);
                acc[2 * c]     = fmaf(mm, lo, acc[2 * c]);
                acc[2 * c + 1] = fmaf(mm, hi, acc[2 * c + 1]);
            }
        }
    }
#pragma unroll
    for (int mk = 8; mk < 64; mk <<= 1)
#pragma unroll
        for (int j = 0; j < 8; ++j) acc[j] += __shfl_xor(acc[j], mk, 64);

    if (eg == 0) {
        float scl = rsqrtf(fmaxf((float)cnt, 1.0f));
        float4 b0 = ((const float4*)b)[h * 2];
        float4 b1 = ((const float4*)b)[h * 2 + 1];
        float4 o0 = {acc[0] * scl + b0.x, acc[1] * scl + b0.y,
                     acc[2] * scl + b0.z, acc[3] * scl + b0.w};
        float4 o1 = {acc[4] * scl + b1.x, acc[5] * scl + b1.y,
                     acc[6] * scl + b1.z, acc[7] * scl + b1.w};
        float4* op = (float4*)(out + (long long)n * 64);
        op[h * 2] = o0;
        op[h * 2 + 1] = o1;
    }
}

extern "C" void kernel_launch(void* const* d_in, const int* in_sizes, int n_in,
                              void* d_out, int out_size, void* d_ws, size_t ws_size,
                              hipStream_t stream) {
    const float* x  = (const float*)d_in[0];
    const int*  idx = (const int*)d_in[1];
    const float* W  = (const float*)d_in[2];
    const float* b  = (const float*)d_in[3];
    float*      out = (float*)d_out;

    const int N = in_sizes[0] / 64;
    const int E = in_sizes[1] / 2;
    const int NB = (N + BSZ - 1) / BSZ;   // 512-node buckets

    int* ws = (int*)d_ws;
    size_t o = 0;
    int* partial = ws + o; o += (size_t)2 * NB * NBLK;
    int* totals  = ws + o; o += 2 * NB;
    int* row_ptr = ws + o; o += N + 1;
    int* entry_pool = ws + o; o += E;
    unsigned short* key_pool = (unsigned short*)(ws + o); o += (E + 1) / 2;
    int* csr = ws + o; o += E;
    o = (o + 63) & ~(size_t)63;
    unsigned short* y = (unsigned short*)(ws + o);

    hist_kernel<<<NBLK, BDIM, 0, stream>>>(idx, E, NB, partial);

    colprefix_kernel<<<(2 * NB * 64 + 255) / 256, 256, 0, stream>>>(
        partial, totals, NB, row_ptr, N, E);

    scatter_kernel<<<NBLK, BDIM, 0, stream>>>(idx, E, NB, partial, totals,
                                              entry_pool, key_pool);

    proj_kernel<<<NB, 1024, 0, stream>>>(x, W, key_pool, totals, y, N, NB, E);

    order_kernel<<<NB, BSZ, 0, stream>>>(entry_pool, totals, row_ptr, csr, N, NB);

    spmm_kernel<<<(N * 64 + 255) / 256, 256, 0, stream>>>(csr, row_ptr, y, b,
                                                          out, N);
}